// Round 9
// baseline (11619.737 us; speedup 1.0000x reference)
//
#include <hip/hip_runtime.h>
#include <hip/hip_bf16.h>
#include <cstddef>
#include <cstdint>

#define Bsz 8
#define Ssz 4096
#define Dsz 768
#define Hh  12
#define Wd  128
#define NBl 32
#define DH  64
#define FFs 3072
#define Vs  512
#define Ls  2
#define GNS 16   // global-attn split chunks (256 keys each)

typedef __attribute__((ext_vector_type(8))) short short8;
typedef __attribute__((ext_vector_type(4))) float f32x4;

typedef __attribute__((address_space(3))) unsigned short as3_ushort;
typedef __attribute__((address_space(1))) unsigned short as1_ushort;

__device__ inline float b2f(unsigned short u) { union { unsigned int i; float f; } x; x.i = ((unsigned int)u) << 16; return x.f; }
__device__ inline float b2f_lo(unsigned int u) { union { unsigned int i; float f; } x; x.i = (u & 0xffffu) << 16; return x.f; }
__device__ inline float b2f_hi(unsigned int u) { union { unsigned int i; float f; } x; x.i = u & 0xffff0000u; return x.f; }
__device__ inline unsigned short f2bu(float f) {
  __hip_bfloat16 h = __float2bfloat16(f);
  return *reinterpret_cast<unsigned short*>(&h);
}
__device__ inline unsigned int pack2(float lo, float hi) {
  return (unsigned int)f2bu(lo) | ((unsigned int)f2bu(hi) << 16);
}
// async global->LDS, 16B per lane; LDS dest = base + lane*16 (wave-uniform base)
__device__ inline void glds16(const unsigned short* g, unsigned short* l) {
  __builtin_amdgcn_global_load_lds((const as1_ushort*)g, (as3_ushort*)l, 16, 0, 0);
}

// ---------- fp32 -> bf16 weight conversion ----------
__global__ __launch_bounds__(256) void k_convw(const float* __restrict__ src,
                                               unsigned short* __restrict__ dst, int n) {
  int i8 = (blockIdx.x * 256 + threadIdx.x) * 8;
  if (i8 >= n) return;
  const float4* s4 = reinterpret_cast<const float4*>(src);
  float4 a = s4[i8 >> 2], b = s4[(i8 >> 2) + 1];
  uint4 o;
  o.x = pack2(a.x, a.y); o.y = pack2(a.z, a.w);
  o.z = pack2(b.x, b.y); o.w = pack2(b.z, b.w);
  reinterpret_cast<uint4*>(dst)[i8 >> 3] = o;
}

// ---------- embedding gather, full batch: fp32 emb rows -> bf16 X ----------
__global__ __launch_bounds__(256) void k_embed(const int* __restrict__ call,
                                               const float* __restrict__ emb,
                                               unsigned short* __restrict__ x) {
  int idx = blockIdx.x * 256 + threadIdx.x;
  int row = idx / 96;
  int c8  = idx % 96;
  int tok = call[row];
  const float4* s4 = reinterpret_cast<const float4*>(emb + (size_t)tok * Dsz);
  float4 a = s4[c8 * 2], b = s4[c8 * 2 + 1];
  uint4 o;
  o.x = pack2(a.x, a.y); o.y = pack2(a.z, a.w);
  o.z = pack2(b.x, b.y); o.w = pack2(b.z, b.w);
  reinterpret_cast<uint4*>(x)[idx] = o;
}

// ==========================================================================
// 256x256 8-wave GEMM, BK=32, 2 blocks/CU (occupancy lever).
// LDS = 4 x [256][32] bf16 = 64 KiB -> 2 resident blocks (16 waves/CU); when
// one block stalls at a barrier/vmcnt the other computes (m97/m114 implicit
// wave-level overlap). BK=32 row stride = 64B, so 16-row fragment reads cover
// contiguous 1KiB -> conflict-free WITHOUT swizzle; staging is plain linear.
// Per tile: boundary {4 glds -> buf p^1, vmcnt(4)} -> barrier -> 12
// ds_read_b128 -> setprio+32 MFMA -> lgkmcnt(0) -> release barrier.
// Epilogue: coalesced LDS-staged bf16 store in two 64 KiB halves.
// ==========================================================================
__global__ __launch_bounds__(512, 4) void k_gemm256(
    const unsigned short* __restrict__ A, const unsigned short* __restrict__ Wb,
    const float* __restrict__ bias0, const float* __restrict__ bias1,
    const float* __restrict__ bias2,
    void* __restrict__ o0, void* __restrict__ o1, void* __restrict__ o2,
    int M, int N, int K, int Ng,
    float a0, float a1, float a2, int relu, int out_fp32) {
  __shared__ unsigned short sh[4][256 * 32];   // A:[0..1], B:[2..3]; 64 KiB

  // XCD-bijective swizzle (all grids divisible by 8)
  const int gx = gridDim.x;
  const int total = gx * (int)gridDim.y;
  const int id = blockIdx.y * gx + blockIdx.x;
  const int swz = (id & 7) * (total >> 3) + (id >> 3);
  const int n0 = (swz % gx) * 256;
  const int m0 = (swz / gx) * 256;

  const int tid = threadIdx.x;
  const int ln = tid & 63;
  const int w = tid >> 6;
  const int wm = w >> 2, wn = w & 3;
  const int mr = ln & 15, quad = ln >> 4;

  // staging: one glds16 covers 16 rows x 4 chunks(16B); 2 instrs/matrix/wave
  const int lr4 = ln >> 2;             // row within 16-row group
  const int lc4 = ln & 3;              // 16B chunk within 64B row
  const unsigned short* srcA[2];
  const unsigned short* srcB[2];
  int ldsOff[2];
#pragma unroll
  for (int i = 0; i < 2; i++) {
    int r = w * 32 + i * 16;
    ldsOff[i] = r * 32;
    srcA[i] = A  + (size_t)(m0 + r + lr4) * K + lc4 * 8;
    srcB[i] = Wb + (size_t)(n0 + r + lr4) * K + lc4 * 8;
  }

  const int rowA = wm * 128 + mr;
  const int rowB = wn * 64 + mr;
  const int q8 = quad * 8;             // k-chunk (8 bf16) within 32-col row

  f32x4 acc[8][4];
#pragma unroll
  for (int i = 0; i < 8; i++)
#pragma unroll
    for (int j = 0; j < 4; j++) acc[i][j] = (f32x4){0.f, 0.f, 0.f, 0.f};

  const int NT = K / 32;

  // prologue: stage K-tile 0 into buf 0 (4 glds/wave)
  glds16(srcA[0], &sh[0][ldsOff[0]]);
  glds16(srcA[1], &sh[0][ldsOff[1]]);
  glds16(srcB[0], &sh[2][ldsOff[0]]);
  glds16(srcB[1], &sh[2][ldsOff[1]]);

  short8 af[8], bf[4];

  for (int t = 0; t < NT; t++) {
    const int p = t & 1;
    const unsigned short* Ap = &sh[p][0];
    const unsigned short* Bp = &sh[2 + p][0];
    const bool pf = (t + 1 < NT);
    const int koff = (t + 1) * 32;

    // boundary: stage tile t+1 into buf p^1, counted wait retires tile t's 4
    if (pf) {
      glds16(srcA[0] + koff, &sh[p ^ 1][ldsOff[0]]);
      glds16(srcA[1] + koff, &sh[p ^ 1][ldsOff[1]]);
      glds16(srcB[0] + koff, &sh[2 + (p ^ 1)][ldsOff[0]]);
      glds16(srcB[1] + koff, &sh[2 + (p ^ 1)][ldsOff[1]]);
      asm volatile("s_waitcnt vmcnt(4)" ::: "memory");
    } else {
      asm volatile("s_waitcnt vmcnt(0)" ::: "memory");
    }
    __builtin_amdgcn_sched_barrier(0);
    __builtin_amdgcn_s_barrier();             // tile t visible to all waves

#pragma unroll
    for (int i = 0; i < 8; i++)
      af[i] = *reinterpret_cast<const short8*>(&Ap[(rowA + i * 16) * 32 + q8]);
#pragma unroll
    for (int j = 0; j < 4; j++)
      bf[j] = *reinterpret_cast<const short8*>(&Bp[(rowB + j * 16) * 32 + q8]);

    __builtin_amdgcn_s_setprio(1);
#pragma unroll
    for (int i = 0; i < 8; i++)
#pragma unroll
      for (int j = 0; j < 4; j++)
        acc[i][j] = __builtin_amdgcn_mfma_f32_16x16x32_bf16(af[i], bf[j], acc[i][j], 0, 0, 0);
    __builtin_amdgcn_s_setprio(0);
    asm volatile("s_waitcnt lgkmcnt(0)" ::: "memory");
    __builtin_amdgcn_sched_barrier(0);
    __builtin_amdgcn_s_barrier();             // release buf p for t+1 staging
  }

  // ---- epilogue ----
  const int grp = n0 / Ng;                    // uniform per block
  const int colbase = n0 - grp * Ng;
  const float* bp = (grp == 0) ? bias0 : (grp == 1) ? bias1 : bias2;
  const float al = (grp == 0) ? a0 : (grp == 1) ? a1 : a2;
  void* op = (grp == 0) ? o0 : (grp == 1) ? o1 : o2;
  const int colg = colbase + wn * 64 + mr;

  if (out_fp32) {
    // classifier path: scalar fp32 stores (1 small dispatch)
#pragma unroll
    for (int nf = 0; nf < 4; nf++) {
      float bv = bp[colg + nf * 16];
#pragma unroll
      for (int mf = 0; mf < 8; mf++) {
        int rowb = m0 + wm * 128 + mf * 16 + quad * 4;
#pragma unroll
        for (int r = 0; r < 4; r++) {
          float v = (acc[mf][nf][r] + bv) * al;
          if (relu) v = fmaxf(v, 0.f);
          reinterpret_cast<float*>(op)[(size_t)(rowb + r) * Ng + colg + nf * 16] = v;
        }
      }
    }
  } else {
    // bf16 path: stage 128x256 half-tiles through the 64 KiB LDS, coalesced out.
    // swizzled addr(row, col8) = row*256 + (((col8&24)|((col8^row)&7))<<3)
    unsigned short* sh0 = &sh[0][0];
    unsigned short* op16 = reinterpret_cast<unsigned short*>(op);
#pragma unroll
    for (int h = 0; h < 2; h++) {
      if (wm == h) {
#pragma unroll
        for (int nf = 0; nf < 4; nf++) {
          float bv = bp[colg + nf * 16];
          int col = wn * 64 + nf * 16 + mr;
          int col8 = col >> 3, c7 = col & 7;
#pragma unroll
          for (int mf = 0; mf < 8; mf++) {
#pragma unroll
            for (int r = 0; r < 4; r++) {
              float v = (acc[mf][nf][r] + bv) * al;
              if (relu) v = fmaxf(v, 0.f);
              int row_l = mf * 16 + quad * 4 + r;
              sh0[row_l * 256 + (((col8 & 24) | ((col8 ^ row_l) & 7)) << 3) + c7] = f2bu(v);
            }
          }
        }
      }
      __syncthreads();
#pragma unroll
      for (int it = 0; it < 8; it++) {
        int g = it * 512 + tid;               // 4096 groups of 8 cols
        int row = g >> 5, col8 = g & 31;
        uint4 vv = *reinterpret_cast<const uint4*>(
            sh0 + row * 256 + (((col8 & 24) | ((col8 ^ row) & 7)) << 3));
        *reinterpret_cast<uint4*>(op16 + (size_t)(m0 + h * 128 + row) * Ng + colbase + col8 * 8) = vv;
      }
      __syncthreads();
    }
  }
}

// ==========================================================================
// Banded attention, MFMA flash-style (unchanged, proven).
// ==========================================================================

template<int NTT, bool PSEUDO>
__device__ __forceinline__ void chunk_qksm(
    const unsigned short* __restrict__ Ks, unsigned short* __restrict__ Pw,
    const short8 (&qf)[2][2], f32x4 (&o)[2][4],
    float (&mrow)[2][4], float (&lrow)[2][4],
    int RB, int pos0, int relb, int g, int cl) {
  f32x4 S[2][NTT];
#pragma unroll
  for (int mt = 0; mt < 2; mt++)
#pragma unroll
    for (int nt = 0; nt < NTT; nt++) S[mt][nt] = (f32x4){0.f, 0.f, 0.f, 0.f};

  short8 kf[NTT][2];
#pragma unroll
  for (int nt = 0; nt < NTT; nt++) {
    int row = RB + nt * 16 + cl;
    int f2 = (row ^ (row >> 2)) & 7;
#pragma unroll
    for (int ks = 0; ks < 2; ks++)
      kf[nt][ks] = *reinterpret_cast<const short8*>(&Ks[row * 64 + (((ks * 4 + g) ^ f2) << 3)]);
  }
#pragma unroll
  for (int mt = 0; mt < 2; mt++)
#pragma unroll
    for (int nt = 0; nt < NTT; nt++)
#pragma unroll
      for (int ks = 0; ks < 2; ks++)
        S[mt][nt] = __builtin_amdgcn_mfma_f32_16x16x32_bf16(qf[mt][ks], kf[nt][ks], S[mt][nt], 0, 0, 0);

  // mask: C-layout is col(key)=lane&15, row(query)=(lane>>4)*4 + reg
#pragma unroll
  for (int mt = 0; mt < 2; mt++) {
#pragma unroll
    for (int nt = 0; nt < NTT; nt++) {
      int pos = pos0 + nt * 16 + cl;
      bool posok = ((unsigned)pos) < (unsigned)Ssz;
      float pb = (pos == 0) ? -10000.f : 0.f;
#pragma unroll
      for (int r = 0; r < 4; r++) {
        float s = S[mt][nt][r];
        if (PSEUDO) {
          s = (nt == 0 && cl == 0) ? s : -1e30f;   // only the global key, no bias
        } else {
          int rel = relb + (nt - mt) * 16 - r;     // key_band_idx - query_idx
          s = (posok && ((unsigned)rel <= 256u)) ? (s + pb) : -1e30f;
        }
        S[mt][nt][r] = s;
      }
    }
    // online softmax per query row (row state replicated across 16-lane group)
#pragma unroll
    for (int r = 0; r < 4; r++) {
      float cm = S[mt][0][r];
#pragma unroll
      for (int nt = 1; nt < NTT; nt++) cm = fmaxf(cm, S[mt][nt][r]);
      cm = fmaxf(cm, __shfl_xor(cm, 1));
      cm = fmaxf(cm, __shfl_xor(cm, 2));
      cm = fmaxf(cm, __shfl_xor(cm, 4));
      cm = fmaxf(cm, __shfl_xor(cm, 8));
      float mo = mrow[mt][r];
      float mn = fmaxf(mo, cm);
      float scl = __expf(mo - mn);
      mrow[mt][r] = mn;
      lrow[mt][r] *= scl;
#pragma unroll
      for (int dt = 0; dt < 4; dt++) o[mt][dt][r] *= scl;
      int prow = mt * 16 + g * 4 + r;
      int f2p = (prow ^ (prow >> 2)) & 7;
#pragma unroll
      for (int nt = 0; nt < NTT; nt++) {
        float p = __expf(S[mt][nt][r] - mn);
        lrow[mt][r] += p;
        int pcol = nt * 16 + cl;
        Pw[prow * 64 + (((pcol >> 3) ^ f2p) << 3) + (pcol & 7)] = f2bu(p);
      }
    }
  }
}

template<int KS2>
__device__ __forceinline__ void chunk_pv(
    const unsigned short* __restrict__ Vt, const unsigned short* __restrict__ Pw,
    f32x4 (&o)[2][4], int g, int cl) {
  short8 vf[4][KS2];
#pragma unroll
  for (int dt = 0; dt < 4; dt++) {
    int d = dt * 16 + cl;
    int f2 = (d ^ (d >> 2)) & 7;
#pragma unroll
    for (int ks = 0; ks < KS2; ks++)
      vf[dt][ks] = *reinterpret_cast<const short8*>(&Vt[d * 64 + (((ks * 4 + g) ^ f2) << 3)]);
  }
  short8 pf[2][KS2];
#pragma unroll
  for (int mt = 0; mt < 2; mt++) {
    int prow = mt * 16 + cl;
    int f2 = (prow ^ (prow >> 2)) & 7;
#pragma unroll
    for (int ks = 0; ks < KS2; ks++)
      pf[mt][ks] = *reinterpret_cast<const short8*>(&Pw[prow * 64 + (((ks * 4 + g) ^ f2) << 3)]);
  }
#pragma unroll
  for (int mt = 0; mt < 2; mt++)
#pragma unroll
    for (int dt = 0; dt < 4; dt++)
#pragma unroll
      for (int ks = 0; ks < KS2; ks++)
        o[mt][dt] = __builtin_amdgcn_mfma_f32_16x16x32_bf16(pf[mt][ks], vf[dt][ks], o[mt][dt], 0, 0, 0);
}

__global__ __launch_bounds__(256, 2) void k_band_attn(const unsigned short* __restrict__ K,
                                                      const unsigned short* __restrict__ V,
                                                      unsigned short* __restrict__ Q /* in & out */) {
  __shared__ unsigned short Ks[416 * 64];     // 52 KB: 384 band rows + 32 global rows
  __shared__ unsigned short Vt[64 * 64];      // 8 KB: transposed V chunk [d][key]
  __shared__ unsigned short Pb[4][32 * 64];   // 16 KB: per-wave P tiles

  // XCD-bijective swizzle (3072 = 8 * 384): neighbor n-blocks share one L2
  const int blk = ((int)blockIdx.x & 7) * 384 + ((int)blockIdx.x >> 3);
  const int n = blk & 31;
  const int h = (blk >> 5) % Hh;
  const int b = blk / (NBl * Hh);
  const int tid = threadIdx.x;
  const int ln = tid & 63;
  const int w = tid >> 6;
  const int g = ln >> 4;
  const int cl = ln & 15;
  const size_t headoff = (size_t)b * Ssz * Dsz + (size_t)h * DH;

  // ---- stage K band + global rows via global_load_lds (pre-swizzled src) ----
#pragma unroll
  for (int it = 0; it < 13; it++) {
    int rb = it * 32 + w * 8;                 // wave-uniform row base, 8 rows/instr
    int row = rb + (ln >> 3);
    int pos = (row < 384) ? (n - 1) * Wd + row : row - 384;
    pos = pos < 0 ? 0 : (pos > Ssz - 1 ? Ssz - 1 : pos);   // clamped rows are masked
    int seg = (ln & 7) ^ ((row ^ (row >> 2)) & 7);
    glds16(K + headoff + (size_t)pos * Dsz + seg * 8, &Ks[rb * 64]);
  }

  // ---- Q fragments (A-layout: row=cl, k=g*8+j per 32-wide slice) ----
  short8 qf[2][2];
  {
    const unsigned short* qb = Q + headoff + (size_t)(n * Wd + w * 32 + cl) * Dsz + g * 8;
#pragma unroll
    for (int mt = 0; mt < 2; mt++)
#pragma unroll
      for (int ks = 0; ks < 2; ks++)
        qf[mt][ks] = *reinterpret_cast<const short8*>(qb + (size_t)mt * 16 * Dsz + ks * 32);
  }

  f32x4 o[2][4];
  float mrow[2][4], lrow[2][4];
#pragma unroll
  for (int mt = 0; mt < 2; mt++) {
#pragma unroll
    for (int r = 0; r < 4; r++) { mrow[mt][r] = -1e30f; lrow[mt][r] = 0.f; }
#pragma unroll
    for (int dt = 0; dt < 4; dt++) o[mt][dt] = (f32x4){0.f, 0.f, 0.f, 0.f};
  }

  unsigned short* Pw = &Pb[w][0];
  const int relbase = cl - w * 32 - g * 4;
  const int key0 = 16 * w + (ln >> 3);        // wave w stages keys 16w..16w+15
  const int dseg = ln & 7;

  // prefetch V for pseudo chunk (pos 0..63, all valid)
  uint4 vreg[2];
#pragma unroll
  for (int it = 0; it < 2; it++)
    vreg[it] = *reinterpret_cast<const uint4*>(V + headoff + (size_t)(key0 + it * 8) * Dsz + dseg * 8);

  for (int cc = 0; cc < 7; cc++) {
    // write staged V regs -> Vt[d][key], rotation-free scatter
#pragma unroll
    for (int it = 0; it < 2; it++) {
      int key = key0 + it * 8;
      unsigned int vw_[4] = {vreg[it].x, vreg[it].y, vreg[it].z, vreg[it].w};
#pragma unroll
      for (int j = 0; j < 8; j++) {
        int d = dseg * 8 + j;
        int slot = (key >> 3) ^ ((d ^ (d >> 2)) & 7);
        Vt[d * 64 + (slot << 3) + (key & 7)] = (unsigned short)(vw_[j >> 1] >> ((j & 1) * 16));
      }
    }
    __syncthreads();   // Vt ready (and, at cc==0, drains Ks glds)

    if (cc == 0) {
      chunk_qksm<2, true>(Ks, Pw, qf, o, mrow, lrow, 384, 0, 0, g, cl);
    } else {
      int c = cc - 1;
      chunk_qksm<4, false>(Ks, Pw, qf, o, mrow, lrow, c * 64,
                           (n - 1) * Wd + c * 64, relbase + c * 64, g, cl);
    }

    // T14: issue next chunk's V loads now; PV below hides the HBM latency
    if (cc < 6) {
      int pos0n = (n - 1) * Wd + cc * 64;     // next chunk is band c = cc
#pragma unroll
      for (int it = 0; it < 2; it++) {
        int pos = pos0n + key0 + it * 8;
        pos = pos < 0 ? 0 : (pos > Ssz - 1 ? Ssz - 1 : pos);
        vreg[it] = *reinterpret_cast<const uint4*>(V + headoff + (size_t)pos * Dsz + dseg * 8);
      }
    }

    if (cc == 0) chunk_pv<1>(Vt, Pw, o, g, cl);
    else         chunk_pv<2>(Vt, Pw, o, g, cl);
    __syncthreads();   // all waves done reading Vt before next overwrite
  }

  // ---- epilogue: reduce l across 16-lane group, normalize, store bf16 ----
#pragma unroll
  for (int mt = 0; mt < 2; mt++)
#pragma unroll
    for (int r = 0; r < 4; r++) {
      float ls = lrow[mt][r];
      ls += __shfl_xor(ls, 1);
      ls += __shfl_xor(ls, 2);
      ls += __shfl_xor(ls, 4);
      ls += __shfl_xor(ls, 8);
      float inv = 1.f / ls;
      int qrow = n * Wd + w * 32 + mt * 16 + g * 4 + r;
      if (qrow != 0) {                        // row 0 rewritten by global attn
        unsigned short* dst = Q + headoff + (size_t)qrow * Dsz;
#pragma unroll
        for (int dt = 0; dt < 4; dt++)
          dst[dt * 16 + cl] = f2bu(o[mt][dt][r] * inv);
      }
    }
}

// ==========================================================================
// Global-token attention, split-K flash-decode style (unchanged, proven).
// ==========================================================================
__global__ __launch_bounds__(256) void k_gattn_part(const unsigned short* __restrict__ K,
                                                    const unsigned short* __restrict__ V,
                                                    const unsigned short* __restrict__ Q,
                                                    float* __restrict__ part) {
  __shared__ float q0[64];
  __shared__ float pj[256];
  __shared__ float red[256];
  const int blk = blockIdx.x;
  const int c = blk & (GNS - 1);
  const int h = (blk / GNS) % Hh;
  const int b = blk / (GNS * Hh);
  const int t = threadIdx.x;
  const size_t base = (size_t)b * Ssz * Dsz + (size_t)h * DH;
  if (t < 64) q0[t] = b2f(Q[base + t]);
  __syncthreads();

  const int j = c * 256 + t;
  const uint4* kp = reinterpret_cast<const uint4*>(K + base + (size_t)j * Dsz);
  float acc = 0.f;
#pragma unroll
  for (int u = 0; u < 8; u++) {
    uint4 w = kp[u];
    acc += q0[u*8+0]*b2f_lo(w.x) + q0[u*8+1]*b2f_hi(w.x)
         + q0[u*8+2]*b2f_lo(w.y) + q0[u*8+3]*b2f_hi(w.y)
         + q0[u*8+4]*b2f_lo(w.z) + q0[u*8+5]*b2f_hi(w.z)
         + q0[u*8+6]*b2f_lo(w.w) + q0[u*8+7]*b2f_hi(w.w);
  }
  red[t] = acc;
  __syncthreads();
  for (int s2 = 128; s2 > 0; s2 >>= 1) {
    if (t < s2) red[t] = fmaxf(red[t], red[t + s2]);
    __syncthreads();
  }
  float m = red[0];
  __syncthreads();
  float p = __expf(acc - m);
  pj[t] = p;
  red[t] = p;
  __syncthreads();
  for (int s2 = 128; s2 > 0; s2 >>= 1) {
    if (t < s2) red[t] += red[t + s2];
    __syncthreads();
  }
  float l = red[0];
  __syncthreads();

  const int d  = t & 63;
  const int gq = t >> 6;
  float oa = 0.f;
  for (int jj = gq * 64; jj < gq * 64 + 64; jj++)
    oa += pj[jj] * b2f(V[base + (size_t)(c * 256 + jj) * Dsz + d]);
  red[t] = oa;
  __syncthreads();

  float* P = part + (size_t)((b * Hh + h) * GNS + c) * 66;
  if (t < 64) P[2 + t] = red[t] + red[64 + t] + red[128 + t] + red[192 + t];
  if (t == 0) { P[0] = m; P[1] = l; }
}

__global__ __launch_bounds__(64) void k_gattn_comb(const float* __restrict__ part,
                                                   unsigned short* __restrict__ Q) {
  const int b = blockIdx.x / Hh;
  const int h = blockIdx.x % Hh;
  const int t = threadIdx.x;   // d
  const float* P = part + (size_t)(b * Hh + h) * GNS * 66;
  float M = -1e30f;
#pragma unroll
  for (int cc = 0; cc < GNS; cc++) M = fmaxf(M, P[cc * 66]);
  float L = 0.f, o = 0.f;
#pragma unroll
  for (int cc = 0; cc < GNS; cc++) {
    float e = __expf(P[cc * 66] - M);
    L += P[cc * 66 + 1] * e;
    o += P[cc * 66 + 2 + t] * e;
  }
  const size_t base = (size_t)b * Ssz * Dsz + (size_t)h * DH;
  Q[base + t] = f2bu(o / L);
}

// ---------- residual add + LayerNorm (wave/row), vectorized loads ---------
__global__ __launch_bounds__(256) void k_ln(const unsigned short* __restrict__ x,
                                            const unsigned short* __restrict__ res,
                                            const float* __restrict__ g,
                                            const float* __restrict__ bta,
                                            unsigned short* out) {
  const int row  = blockIdx.x * 4 + (threadIdx.x >> 6);
  const int lane = threadIdx.x & 63;
  const size_t off = (size_t)row * Dsz;
  float v[3][4];
#pragma unroll
  for (int r = 0; r < 3; r++) {
    int d = lane * 4 + r * 256;
    ushort4 xv = *reinterpret_cast<const ushort4*>(x + off + d);
    v[r][0] = b2f(xv.x); v[r][1] = b2f(xv.y);
    v[r][2] = b2f(xv.z); v[r][3] = b2f(xv.w);
    if (res) {
      ushort4 rv = *reinterpret_cast<const ushort4*>(res + off + d);
      v[r][0] += b2f(rv.x); v[r][1] += b2f(rv.y);
      v[r][2] += b2f(rv.z); v[r][3] += b2f(rv.w);
    }
  }
  float s = 0.f;
#pragma unroll
  for (int r = 0; r < 3; r++)
#pragma unroll
    for (int j = 0; j < 4; j++) s += v[r][j];
#pragma unroll
  for (int o2 = 32; o2 > 0; o2 >>= 1) s += __shfl_xor(s, o2);
  float mean = s * (1.f / Dsz);
  float vs = 0.f;
#pragma unroll
  for (int r = 0; r < 3; r++)
#pragma unroll
    for (int j = 0; j < 4; j++) { float dd = v[r][j] - mean; vs += dd * dd; }
#pragma unroll
  for (int o2 = 32; o2 > 0; o2 >>= 1) vs += __shfl_xor(vs, o2);
  float rstd = rsqrtf(vs * (1.f / Dsz) + 1e-5f);
#pragma unroll
  for (int r = 0; r < 3; r++) {
    int d = lane * 4 + r * 256;
    float4 gv = *reinterpret_cast<const float4*>(g + d);
    float4 bv = *reinterpret_cast<const float4*>(bta + d);
    ushort4 ov;
    ov.x = f2bu((v[r][0] - mean) * rstd * gv.x + bv.x);
    ov.y = f2bu((v[r][1] - mean) * rstd * gv.y + bv.y);
    ov.z = f2bu((v[r][2] - mean) * rstd * gv.z + bv.z);
    ov.w = f2bu((v[r][3] - mean) * rstd * gv.w + bv.w);
    *reinterpret_cast<ushort4*>(out + off + d) = ov;
  }
}

// ---------------- host ----------------
static inline unsigned cg8(int n) { return (unsigned)((n / 8 + 255) / 256); }

extern "C" void kernel_launch(void* const* d_in, const int* in_sizes, int n_in,
                              void* d_out, int out_size, void* d_ws, size_t ws_size,
                              hipStream_t stream) {
  const int*   call = (const int*)d_in[0];
  const float* emb  = (const float*)d_in[9];
  const float* Wq = (const float*)d_in[10]; const float* bq = (const float*)d_in[11];
  const float* Wk = (const float*)d_in[12]; const float* bk = (const float*)d_in[13];
  const float* Wv = (const float*)d_in[14]; const float* bv = (const float*)d_in[15];
  const float* Wo = (const float*)d_in[16]; const float* bo = (const float*)d_in[17];
  const float* W1 = (const float*)d_in[18]; const float* b1 = (const float*)d_in[19];
  const float* W2 = (const float*)d_in[20]; const float* b2 = (const float*)d_in[21];
  const float* g1 = (const float*)d_in[22]; const float* bt1 = (const float*)d_in[23];
  const float* g2 = (const float*)d_in[24]; const float* bt2 = (const float*)d_in[25];
  const float* gf = (const float*)d_in[26]; const float* btf = (const float*)d_in[27];
  const float* Wc = (const float*)d_in[28]; const float* bc = (const float*)d_in[29];

  const int DD = Dsz * Dsz;                  // 589824
  const int FD = FFs * Dsz;                  // 2359296
  const int M  = Bsz * Ssz;                  // 32768
  const size_t MD = (size_t)M * Dsz;         // 25165824

  unsigned short* ws = (unsigned short*)d_ws;
  unsigned short* X  = ws;              // MD
  unsigned short* Qb = X  + MD;         // MD
  unsigned short* Kb = Qb + MD;         // MD
  unsigned short* Vb = Kb + MD;         // MD
  unsigned short* cW = Vb + MD;         // 14548992 bf16 weights
  unsigned short* cQKV = cW;                              // [L][3][D][D]
  unsigned short* cWo  = cQKV + (size_t)3 * Ls * DD;
  unsigned short* cW1  = cWo + (size_t)Ls * DD;
  unsigned short* cW2  = cW1 + (size_t)Ls * FD;
  unsigned short* cWc  = cW2 + (size_t)Ls * FD;
  float* gpart = (float*)(cWc + (size_t)Vs * Dsz);   // 96*GNS*66 fp32
  unsigned short* Hb  = Kb;             // FFN intermediate overlays Kb..Vb
  // total ws: 4*MD + 14548992 elems + 406KB = ~220.4 MiB (< proven-safe 240 MiB)

  // weights -> bf16 (once per launch); QKV repacked per-layer-contiguous
  for (int l = 0; l < Ls; l++) {
    k_convw<<<cg8(DD), 256, 0, stream>>>(Wq + (size_t)l*DD, cQKV + (size_t)(l*3+0)*DD, DD);
    k_convw<<<cg8(DD), 256, 0, stream>>>(Wk + (size_t)l*DD, cQKV + (size_t)(l*3+1)*DD, DD);
    k_convw<<<cg8(DD), 256, 0, stream>>>(Wv + (size_t)l*DD, cQKV + (size_t)(l*3+2)*DD, DD);
  }
  k_convw<<<cg8(Ls*DD), 256, 0, stream>>>(Wo, cWo, Ls*DD);
  k_convw<<<cg8(Ls*FD), 256, 0, stream>>>(W1, cW1, Ls*FD);
  k_convw<<<cg8(Ls*FD), 256, 0, stream>>>(W2, cW2, Ls*FD);
  k_convw<<<cg8(Vs*Dsz), 256, 0, stream>>>(Wc, cWc, Vs*Dsz);

  k_embed<<<(unsigned)(M * 96 / 256), 256, 0, stream>>>(call, emb, X);

  for (int l = 0; l < Ls; l++) {
    // fused QKV: N=2304 (groups of 768 -> Qb, Kb, Vb); Q scaled by 1/8
    k_gemm256<<<dim3(2304/256, M/256), 512, 0, stream>>>(X, cQKV + (size_t)l*3*DD,
        bq + l*Dsz, bk + l*Dsz, bv + l*Dsz, Qb, Kb, Vb,
        M, 2304, Dsz, Dsz, 0.125f, 1.f, 1.f, 0, 0);
    // global-attn partials read Q row 0 (band attn never writes row 0)
    k_gattn_part<<<Bsz * Hh * GNS, 256, 0, stream>>>(Kb, Vb, Qb, gpart);
    k_band_attn<<<Bsz * Hh * NBl, 256, 0, stream>>>(Kb, Vb, Qb);
    k_gattn_comb<<<Bsz * Hh, 64, 0, stream>>>(gpart, Qb);
    // attn projection: Qb @ Wo -> Kb (K dead after attention)
    k_gemm256<<<dim3(Dsz/256, M/256), 512, 0, stream>>>(Qb, cWo + (size_t)l*DD,
        bo + l*Dsz, bo + l*Dsz, bo + l*Dsz, Kb, Kb, Kb,
        M, Dsz, Dsz, Dsz, 1.f, 1.f, 1.f, 0, 0);
    k_ln<<<M/4, 256, 0, stream>>>(X, Kb, g1 + l*Dsz, bt1 + l*Dsz, X);
    for (int hf = 0; hf < 2; hf++) {
      const size_t mo = (size_t)hf * (M/2);
      k_gemm256<<<dim3(FFs/256, (M/2)/256), 512, 0, stream>>>(X + mo*Dsz,
          cW1 + (size_t)l*FD, b1 + l*FFs, b1 + l*FFs, b1 + l*FFs, Hb, Hb, Hb,
          M/2, FFs, Dsz, FFs, 1.f, 1.f, 1.f, 1, 0);
      k_gemm256<<<dim3(Dsz/256, (M/2)/256), 512, 0, stream>>>(Hb,
          cW2 + (size_t)l*FD, b2 + l*Dsz, b2 + l*Dsz, b2 + l*Dsz,
          Qb + mo*Dsz, Qb + mo*Dsz, Qb + mo*Dsz,
          M/2, Dsz, FFs, Dsz, 1.f, 1.f, 1.f, 0, 0);
    }
    k_ln<<<M/4, 256, 0, stream>>>(X, Qb, g2 + l*Dsz, bt2 + l*Dsz, X);
  }

  k_ln<<<M/4, 256, 0, stream>>>(X, nullptr, gf, btf, Qb);
  k_gemm256<<<dim3(Vs/256, M/256), 512, 0, stream>>>(Qb, cWc,
      bc, bc, bc, (float*)d_out, (float*)d_out, (float*)d_out,
      M, Vs, Dsz, Vs, 1.f, 1.f, 1.f, 0, 1);
}

// Round 10
// 1821.931 us; speedup vs baseline: 6.3777x; 6.3777x over previous
//
#include <hip/hip_runtime.h>
#include <hip/hip_bf16.h>
#include <cstddef>
#include <cstdint>

#define Bsz 8
#define Ssz 4096
#define Dsz 768
#define Hh  12
#define Wd  128
#define NBl 32
#define DH  64
#define FFs 3072
#define Vs  512
#define Ls  2
#define GNS 16   // global-attn split chunks (256 keys each)

typedef __attribute__((ext_vector_type(8))) short short8;
typedef __attribute__((ext_vector_type(4))) float f32x4;

typedef __attribute__((address_space(3))) unsigned short as3_ushort;
typedef __attribute__((address_space(1))) unsigned short as1_ushort;

__device__ inline float b2f(unsigned short u) { union { unsigned int i; float f; } x; x.i = ((unsigned int)u) << 16; return x.f; }
__device__ inline float b2f_lo(unsigned int u) { union { unsigned int i; float f; } x; x.i = (u & 0xffffu) << 16; return x.f; }
__device__ inline float b2f_hi(unsigned int u) { union { unsigned int i; float f; } x; x.i = u & 0xffff0000u; return x.f; }
__device__ inline unsigned short f2bu(float f) {
  __hip_bfloat16 h = __float2bfloat16(f);
  return *reinterpret_cast<unsigned short*>(&h);
}
__device__ inline unsigned int pack2(float lo, float hi) {
  return (unsigned int)f2bu(lo) | ((unsigned int)f2bu(hi) << 16);
}
// async global->LDS, 16B per lane; LDS dest = base + lane*16 (wave-uniform base)
__device__ inline void glds16(const unsigned short* g, unsigned short* l) {
  __builtin_amdgcn_global_load_lds((const as1_ushort*)g, (as3_ushort*)l, 16, 0, 0);
}

// ---------- fp32 -> bf16 weight conversion ----------
__global__ __launch_bounds__(256) void k_convw(const float* __restrict__ src,
                                               unsigned short* __restrict__ dst, int n) {
  int i8 = (blockIdx.x * 256 + threadIdx.x) * 8;
  if (i8 >= n) return;
  const float4* s4 = reinterpret_cast<const float4*>(src);
  float4 a = s4[i8 >> 2], b = s4[(i8 >> 2) + 1];
  uint4 o;
  o.x = pack2(a.x, a.y); o.y = pack2(a.z, a.w);
  o.z = pack2(b.x, b.y); o.w = pack2(b.z, b.w);
  reinterpret_cast<uint4*>(dst)[i8 >> 3] = o;
}

// ---------- embedding gather, full batch: fp32 emb rows -> bf16 X ----------
__global__ __launch_bounds__(256) void k_embed(const int* __restrict__ call,
                                               const float* __restrict__ emb,
                                               unsigned short* __restrict__ x) {
  int idx = blockIdx.x * 256 + threadIdx.x;
  int row = idx / 96;
  int c8  = idx % 96;
  int tok = call[row];
  const float4* s4 = reinterpret_cast<const float4*>(emb + (size_t)tok * Dsz);
  float4 a = s4[c8 * 2], b = s4[c8 * 2 + 1];
  uint4 o;
  o.x = pack2(a.x, a.y); o.y = pack2(a.z, a.w);
  o.z = pack2(b.x, b.y); o.w = pack2(b.z, b.w);
  reinterpret_cast<uint4*>(x)[idx] = o;
}

// ==========================================================================
// 256x256x64 8-wave GEMM (round-6 proven configuration, unchanged).
// Per-phase glds staging + counted vmcnt(2); setprio around MFMA clusters;
// LDS-staged coalesced bf16 epilogue (WRITE_SIZE = ideal).
// ==========================================================================
__global__ __launch_bounds__(512, 2) void k_gemm256(
    const unsigned short* __restrict__ A, const unsigned short* __restrict__ Wb,
    const float* __restrict__ bias0, const float* __restrict__ bias1,
    const float* __restrict__ bias2,
    void* __restrict__ o0, void* __restrict__ o1, void* __restrict__ o2,
    int M, int N, int K, int Ng,
    float a0, float a1, float a2, int relu, int out_fp32) {
  __shared__ unsigned short As[2][256 * 64];
  __shared__ unsigned short Bs[2][256 * 64];

  // XCD-bijective swizzle (all grids divisible by 8)
  const int gx = gridDim.x;
  const int total = gx * (int)gridDim.y;
  const int id = blockIdx.y * gx + blockIdx.x;
  const int swz = (id & 7) * (total >> 3) + (id >> 3);
  const int n0 = (swz % gx) * 256;
  const int m0 = (swz / gx) * 256;

  const int tid = threadIdx.x;
  const int ln = tid & 63;
  const int w = tid >> 6;
  const int wm = w >> 2, wn = w & 3;
  const int mr = ln & 15, quad = ln >> 4;

  // staging lane constants: one glds16 covers 8 rows x 8 chunks(16B)
  const int lr = ln >> 3;              // row within 8-row group
  const int lc = (ln & 7) ^ lr;        // pre-swizzled source chunk
  const unsigned short* srcA[4];
  const unsigned short* srcB[4];
  int ldsOff[4];
#pragma unroll
  for (int hi = 0; hi < 2; hi++)
#pragma unroll
    for (int i = 0; i < 2; i++) {
      int r = hi * 128 + (w * 2 + i) * 8;
      ldsOff[hi * 2 + i] = r * 64;
      srcA[hi * 2 + i] = A  + (size_t)(m0 + r + lr) * K + lc * 8;
      srcB[hi * 2 + i] = Wb + (size_t)(n0 + r + lr) * K + lc * 8;
    }

  // frag-read lane constants: off(row,ks) = row*64 + (s0 ^ (ks*32))
  const int s0 = (quad ^ (mr & 7)) * 8;
  const int rowA = wm * 128 + mr;
  const int rowB = wn * 64 + mr;

  f32x4 acc[8][4];
#pragma unroll
  for (int i = 0; i < 8; i++)
#pragma unroll
    for (int j = 0; j < 4; j++) acc[i][j] = (f32x4){0.f, 0.f, 0.f, 0.f};

  const int NT = K / 64;

  // prologue: stage K-tile 0 into buf 0 (A0,A1,B0,B1 halves; 8 glds/wave)
#pragma unroll
  for (int j = 0; j < 4; j++) glds16(srcA[j], &As[0][ldsOff[j]]);
#pragma unroll
  for (int j = 0; j < 4; j++) glds16(srcB[j], &Bs[0][ldsOff[j]]);

  short8 af[4][2];
  short8 bf[2][2][2];

  for (int t = 0; t < NT; t++) {
    const int p = t & 1;
    const unsigned short* Ap = &As[p][0];
    const unsigned short* Bp = &Bs[p][0];
    const bool pf = (t + 1 < NT);
    const int koff = (t + 1) * 64;

    // stage A-half0 of next tile, then counted wait for THIS tile's 8 loads
    if (pf) {
      glds16(srcA[0] + koff, &As[p ^ 1][ldsOff[0]]);
      glds16(srcA[1] + koff, &As[p ^ 1][ldsOff[1]]);
      asm volatile("s_waitcnt vmcnt(2)" ::: "memory");
    } else {
      asm volatile("s_waitcnt vmcnt(0)" ::: "memory");
    }
    __builtin_amdgcn_sched_barrier(0);
    __builtin_amdgcn_s_barrier();             // tile t visible to all waves

    // ---- phase 0: read A-half0 + B-half0, MFMA quadrant (mh0,nh0) ----
#pragma unroll
    for (int i = 0; i < 4; i++) {
      int ro = (rowA + i * 16) * 64;
      af[i][0] = *reinterpret_cast<const short8*>(&Ap[ro + s0]);
      af[i][1] = *reinterpret_cast<const short8*>(&Ap[ro + (s0 ^ 32)]);
    }
#pragma unroll
    for (int j = 0; j < 2; j++) {
      int ro = (rowB + j * 16) * 64;
      bf[0][j][0] = *reinterpret_cast<const short8*>(&Bp[ro + s0]);
      bf[0][j][1] = *reinterpret_cast<const short8*>(&Bp[ro + (s0 ^ 32)]);
    }
    if (pf) {
      glds16(srcA[2] + koff, &As[p ^ 1][ldsOff[2]]);
      glds16(srcA[3] + koff, &As[p ^ 1][ldsOff[3]]);
    }
    __builtin_amdgcn_s_setprio(1);
#pragma unroll
    for (int i = 0; i < 4; i++)
#pragma unroll
      for (int j = 0; j < 2; j++)
#pragma unroll
        for (int ks = 0; ks < 2; ks++)
          acc[i][j] = __builtin_amdgcn_mfma_f32_16x16x32_bf16(af[i][ks], bf[0][j][ks], acc[i][j], 0, 0, 0);
    __builtin_amdgcn_s_setprio(0);
    __builtin_amdgcn_s_barrier();

    // ---- phase 1: read B-half1, MFMA quadrant (mh0,nh1) ----
#pragma unroll
    for (int j = 0; j < 2; j++) {
      int ro = (rowB + (2 + j) * 16) * 64;
      bf[1][j][0] = *reinterpret_cast<const short8*>(&Bp[ro + s0]);
      bf[1][j][1] = *reinterpret_cast<const short8*>(&Bp[ro + (s0 ^ 32)]);
    }
    if (pf) {
      glds16(srcB[0] + koff, &Bs[p ^ 1][ldsOff[0]]);
      glds16(srcB[1] + koff, &Bs[p ^ 1][ldsOff[1]]);
    }
    __builtin_amdgcn_s_setprio(1);
#pragma unroll
    for (int i = 0; i < 4; i++)
#pragma unroll
      for (int j = 0; j < 2; j++)
#pragma unroll
        for (int ks = 0; ks < 2; ks++)
          acc[i][2 + j] = __builtin_amdgcn_mfma_f32_16x16x32_bf16(af[i][ks], bf[1][j][ks], acc[i][2 + j], 0, 0, 0);
    __builtin_amdgcn_s_setprio(0);
    __builtin_amdgcn_s_barrier();

    // ---- phase 2: read A-half1 (overwrite af), MFMA quadrant (mh1,nh1) ----
#pragma unroll
    for (int i = 0; i < 4; i++) {
      int ro = (rowA + (4 + i) * 16) * 64;
      af[i][0] = *reinterpret_cast<const short8*>(&Ap[ro + s0]);
      af[i][1] = *reinterpret_cast<const short8*>(&Ap[ro + (s0 ^ 32)]);
    }
    if (pf) {
      glds16(srcB[2] + koff, &Bs[p ^ 1][ldsOff[2]]);
      glds16(srcB[3] + koff, &Bs[p ^ 1][ldsOff[3]]);
    }
    __builtin_amdgcn_s_setprio(1);
#pragma unroll
    for (int i = 0; i < 4; i++)
#pragma unroll
      for (int j = 0; j < 2; j++)
#pragma unroll
        for (int ks = 0; ks < 2; ks++)
          acc[4 + i][2 + j] = __builtin_amdgcn_mfma_f32_16x16x32_bf16(af[i][ks], bf[1][j][ks], acc[4 + i][2 + j], 0, 0, 0);
    __builtin_amdgcn_s_setprio(0);
    __builtin_amdgcn_s_barrier();

    // ---- phase 3: no reads (af=A1, bf[0]=B0 live), quadrant (mh1,nh0) ----
    __builtin_amdgcn_s_setprio(1);
#pragma unroll
    for (int i = 0; i < 4; i++)
#pragma unroll
      for (int j = 0; j < 2; j++)
#pragma unroll
        for (int ks = 0; ks < 2; ks++)
          acc[4 + i][j] = __builtin_amdgcn_mfma_f32_16x16x32_bf16(af[i][ks], bf[0][j][ks], acc[4 + i][j], 0, 0, 0);
    __builtin_amdgcn_s_setprio(0);
    asm volatile("s_waitcnt lgkmcnt(0)" ::: "memory");
    __builtin_amdgcn_sched_barrier(0);
    __builtin_amdgcn_s_barrier();             // release buf p for t+2 staging
  }

  // ---- epilogue ----
  const int grp = n0 / Ng;                    // uniform per block
  const int colbase = n0 - grp * Ng;
  const float* bp = (grp == 0) ? bias0 : (grp == 1) ? bias1 : bias2;
  const float al = (grp == 0) ? a0 : (grp == 1) ? a1 : a2;
  void* op = (grp == 0) ? o0 : (grp == 1) ? o1 : o2;
  const int colg = colbase + wn * 64 + mr;

  if (out_fp32) {
    // classifier path: scalar fp32 stores (1 small dispatch)
#pragma unroll
    for (int nf = 0; nf < 4; nf++) {
      float bv = bp[colg + nf * 16];
#pragma unroll
      for (int mf = 0; mf < 8; mf++) {
        int rowb = m0 + wm * 128 + mf * 16 + quad * 4;
#pragma unroll
        for (int r = 0; r < 4; r++) {
          float v = (acc[mf][nf][r] + bv) * al;
          if (relu) v = fmaxf(v, 0.f);
          reinterpret_cast<float*>(op)[(size_t)(rowb + r) * Ng + colg + nf * 16] = v;
        }
      }
    }
  } else {
    // bf16 path: stage C tile into As/Bs (exactly 128 KiB), then coalesced out.
    unsigned short* creg = (w < 4) ? (&As[0][0] + w * 8192) : (&Bs[0][0] + (w - 4) * 8192);
#pragma unroll
    for (int nf = 0; nf < 4; nf++) {
      float bv = bp[colg + nf * 16];
      int c = nf * 16 + mr;
#pragma unroll
      for (int mf = 0; mf < 8; mf++) {
#pragma unroll
        for (int r = 0; r < 4; r++) {
          float v = (acc[mf][nf][r] + bv) * al;
          if (relu) v = fmaxf(v, 0.f);
          int row_l = mf * 16 + quad * 4 + r;
          creg[row_l * 64 + (((c >> 3) ^ (row_l & 7)) << 3) + (c & 7)] = f2bu(v);
        }
      }
    }
    __syncthreads();
    unsigned short* op16 = reinterpret_cast<unsigned short*>(op);
#pragma unroll
    for (int it = 0; it < 16; it++) {
      int flat = it * 512 + tid;              // 8192 groups of 8 cols
      int row = flat >> 5;                    // 256 rows, 32 groups/row
      int col = (flat & 31) << 3;
      int wsel = ((row >> 7) << 2) + (col >> 6);
      const unsigned short* rb = (wsel < 4) ? (&As[0][0] + wsel * 8192)
                                            : (&Bs[0][0] + (wsel - 4) * 8192);
      int r_l = row & 127, c_l = col & 63;
      uint4 vv = *reinterpret_cast<const uint4*>(
          rb + r_l * 64 + (((c_l >> 3) ^ (r_l & 7)) << 3));
      *reinterpret_cast<uint4*>(op16 + (size_t)(m0 + row) * Ng + colbase + col) = vv;
    }
  }
}

// ==========================================================================
// Banded attention, MFMA flash-style. Round-6 structure + T5 setprio around
// the QK and PV MFMA clusters (2 independent blocks/CU -> m191 regime).
// ==========================================================================

template<int NTT, bool PSEUDO>
__device__ __forceinline__ void chunk_qksm(
    const unsigned short* __restrict__ Ks, unsigned short* __restrict__ Pw,
    const short8 (&qf)[2][2], f32x4 (&o)[2][4],
    float (&mrow)[2][4], float (&lrow)[2][4],
    int RB, int pos0, int relb, int g, int cl) {
  f32x4 S[2][NTT];
#pragma unroll
  for (int mt = 0; mt < 2; mt++)
#pragma unroll
    for (int nt = 0; nt < NTT; nt++) S[mt][nt] = (f32x4){0.f, 0.f, 0.f, 0.f};

  short8 kf[NTT][2];
#pragma unroll
  for (int nt = 0; nt < NTT; nt++) {
    int row = RB + nt * 16 + cl;
    int f2 = (row ^ (row >> 2)) & 7;
#pragma unroll
    for (int ks = 0; ks < 2; ks++)
      kf[nt][ks] = *reinterpret_cast<const short8*>(&Ks[row * 64 + (((ks * 4 + g) ^ f2) << 3)]);
  }
  __builtin_amdgcn_s_setprio(1);
#pragma unroll
  for (int mt = 0; mt < 2; mt++)
#pragma unroll
    for (int nt = 0; nt < NTT; nt++)
#pragma unroll
      for (int ks = 0; ks < 2; ks++)
        S[mt][nt] = __builtin_amdgcn_mfma_f32_16x16x32_bf16(qf[mt][ks], kf[nt][ks], S[mt][nt], 0, 0, 0);
  __builtin_amdgcn_s_setprio(0);

  // mask: C-layout is col(key)=lane&15, row(query)=(lane>>4)*4 + reg
#pragma unroll
  for (int mt = 0; mt < 2; mt++) {
#pragma unroll
    for (int nt = 0; nt < NTT; nt++) {
      int pos = pos0 + nt * 16 + cl;
      bool posok = ((unsigned)pos) < (unsigned)Ssz;
      float pb = (pos == 0) ? -10000.f : 0.f;
#pragma unroll
      for (int r = 0; r < 4; r++) {
        float s = S[mt][nt][r];
        if (PSEUDO) {
          s = (nt == 0 && cl == 0) ? s : -1e30f;   // only the global key, no bias
        } else {
          int rel = relb + (nt - mt) * 16 - r;     // key_band_idx - query_idx
          s = (posok && ((unsigned)rel <= 256u)) ? (s + pb) : -1e30f;
        }
        S[mt][nt][r] = s;
      }
    }
    // online softmax per query row (row state replicated across 16-lane group)
#pragma unroll
    for (int r = 0; r < 4; r++) {
      float cm = S[mt][0][r];
#pragma unroll
      for (int nt = 1; nt < NTT; nt++) cm = fmaxf(cm, S[mt][nt][r]);
      cm = fmaxf(cm, __shfl_xor(cm, 1));
      cm = fmaxf(cm, __shfl_xor(cm, 2));
      cm = fmaxf(cm, __shfl_xor(cm, 4));
      cm = fmaxf(cm, __shfl_xor(cm, 8));
      float mo = mrow[mt][r];
      float mn = fmaxf(mo, cm);
      float scl = __expf(mo - mn);
      mrow[mt][r] = mn;
      lrow[mt][r] *= scl;
#pragma unroll
      for (int dt = 0; dt < 4; dt++) o[mt][dt][r] *= scl;
      int prow = mt * 16 + g * 4 + r;
      int f2p = (prow ^ (prow >> 2)) & 7;
#pragma unroll
      for (int nt = 0; nt < NTT; nt++) {
        float p = __expf(S[mt][nt][r] - mn);
        lrow[mt][r] += p;
        int pcol = nt * 16 + cl;
        Pw[prow * 64 + (((pcol >> 3) ^ f2p) << 3) + (pcol & 7)] = f2bu(p);
      }
    }
  }
}

template<int KS2>
__device__ __forceinline__ void chunk_pv(
    const unsigned short* __restrict__ Vt, const unsigned short* __restrict__ Pw,
    f32x4 (&o)[2][4], int g, int cl) {
  short8 vf[4][KS2];
#pragma unroll
  for (int dt = 0; dt < 4; dt++) {
    int d = dt * 16 + cl;
    int f2 = (d ^ (d >> 2)) & 7;
#pragma unroll
    for (int ks = 0; ks < KS2; ks++)
      vf[dt][ks] = *reinterpret_cast<const short8*>(&Vt[d * 64 + (((ks * 4 + g) ^ f2) << 3)]);
  }
  short8 pf[2][KS2];
#pragma unroll
  for (int mt = 0; mt < 2; mt++) {
    int prow = mt * 16 + cl;
    int f2 = (prow ^ (prow >> 2)) & 7;
#pragma unroll
    for (int ks = 0; ks < KS2; ks++)
      pf[mt][ks] = *reinterpret_cast<const short8*>(&Pw[prow * 64 + (((ks * 4 + g) ^ f2) << 3)]);
  }
  __builtin_amdgcn_s_setprio(1);
#pragma unroll
  for (int mt = 0; mt < 2; mt++)
#pragma unroll
    for (int dt = 0; dt < 4; dt++)
#pragma unroll
      for (int ks = 0; ks < KS2; ks++)
        o[mt][dt] = __builtin_amdgcn_mfma_f32_16x16x32_bf16(pf[mt][ks], vf[dt][ks], o[mt][dt], 0, 0, 0);
  __builtin_amdgcn_s_setprio(0);
}

__global__ __launch_bounds__(256, 2) void k_band_attn(const unsigned short* __restrict__ K,
                                                      const unsigned short* __restrict__ V,
                                                      unsigned short* __restrict__ Q /* in & out */) {
  __shared__ unsigned short Ks[416 * 64];     // 52 KB: 384 band rows + 32 global rows
  __shared__ unsigned short Vt[64 * 64];      // 8 KB: transposed V chunk [d][key]
  __shared__ unsigned short Pb[4][32 * 64];   // 16 KB: per-wave P tiles

  // XCD-bijective swizzle (3072 = 8 * 384): neighbor n-blocks share one L2
  const int blk = ((int)blockIdx.x & 7) * 384 + ((int)blockIdx.x >> 3);
  const int n = blk & 31;
  const int h = (blk >> 5) % Hh;
  const int b = blk / (NBl * Hh);
  const int tid = threadIdx.x;
  const int ln = tid & 63;
  const int w = tid >> 6;
  const int g = ln >> 4;
  const int cl = ln & 15;
  const size_t headoff = (size_t)b * Ssz * Dsz + (size_t)h * DH;

  // ---- stage K band + global rows via global_load_lds (pre-swizzled src) ----
#pragma unroll
  for (int it = 0; it < 13; it++) {
    int rb = it * 32 + w * 8;                 // wave-uniform row base, 8 rows/instr
    int row = rb + (ln >> 3);
    int pos = (row < 384) ? (n - 1) * Wd + row : row - 384;
    pos = pos < 0 ? 0 : (pos > Ssz - 1 ? Ssz - 1 : pos);   // clamped rows are masked
    int seg = (ln & 7) ^ ((row ^ (row >> 2)) & 7);
    glds16(K + headoff + (size_t)pos * Dsz + seg * 8, &Ks[rb * 64]);
  }

  // ---- Q fragments (A-layout: row=cl, k=g*8+j per 32-wide slice) ----
  short8 qf[2][2];
  {
    const unsigned short* qb = Q + headoff + (size_t)(n * Wd + w * 32 + cl) * Dsz + g * 8;
#pragma unroll
    for (int mt = 0; mt < 2; mt++)
#pragma unroll
      for (int ks = 0; ks < 2; ks++)
        qf[mt][ks] = *reinterpret_cast<const short8*>(qb + (size_t)mt * 16 * Dsz + ks * 32);
  }

  f32x4 o[2][4];
  float mrow[2][4], lrow[2][4];
#pragma unroll
  for (int mt = 0; mt < 2; mt++) {
#pragma unroll
    for (int r = 0; r < 4; r++) { mrow[mt][r] = -1e30f; lrow[mt][r] = 0.f; }
#pragma unroll
    for (int dt = 0; dt < 4; dt++) o[mt][dt] = (f32x4){0.f, 0.f, 0.f, 0.f};
  }

  unsigned short* Pw = &Pb[w][0];
  const int relbase = cl - w * 32 - g * 4;
  const int key0 = 16 * w + (ln >> 3);        // wave w stages keys 16w..16w+15
  const int dseg = ln & 7;

  // prefetch V for pseudo chunk (pos 0..63, all valid)
  uint4 vreg[2];
#pragma unroll
  for (int it = 0; it < 2; it++)
    vreg[it] = *reinterpret_cast<const uint4*>(V + headoff + (size_t)(key0 + it * 8) * Dsz + dseg * 8);

  for (int cc = 0; cc < 7; cc++) {
    // write staged V regs -> Vt[d][key], rotation-free scatter
#pragma unroll
    for (int it = 0; it < 2; it++) {
      int key = key0 + it * 8;
      unsigned int vw_[4] = {vreg[it].x, vreg[it].y, vreg[it].z, vreg[it].w};
#pragma unroll
      for (int j = 0; j < 8; j++) {
        int d = dseg * 8 + j;
        int slot = (key >> 3) ^ ((d ^ (d >> 2)) & 7);
        Vt[d * 64 + (slot << 3) + (key & 7)] = (unsigned short)(vw_[j >> 1] >> ((j & 1) * 16));
      }
    }
    __syncthreads();   // Vt ready (and, at cc==0, drains Ks glds)

    if (cc == 0) {
      chunk_qksm<2, true>(Ks, Pw, qf, o, mrow, lrow, 384, 0, 0, g, cl);
    } else {
      int c = cc - 1;
      chunk_qksm<4, false>(Ks, Pw, qf, o, mrow, lrow, c * 64,
                           (n - 1) * Wd + c * 64, relbase + c * 64, g, cl);
    }

    // T14: issue next chunk's V loads now; PV below hides the HBM latency
    if (cc < 6) {
      int pos0n = (n - 1) * Wd + cc * 64;     // next chunk is band c = cc
#pragma unroll
      for (int it = 0; it < 2; it++) {
        int pos = pos0n + key0 + it * 8;
        pos = pos < 0 ? 0 : (pos > Ssz - 1 ? Ssz - 1 : pos);
        vreg[it] = *reinterpret_cast<const uint4*>(V + headoff + (size_t)pos * Dsz + dseg * 8);
      }
    }

    if (cc == 0) chunk_pv<1>(Vt, Pw, o, g, cl);
    else         chunk_pv<2>(Vt, Pw, o, g, cl);
    __syncthreads();   // all waves done reading Vt before next overwrite
  }

  // ---- epilogue: reduce l across 16-lane group, normalize, store bf16 ----
#pragma unroll
  for (int mt = 0; mt < 2; mt++)
#pragma unroll
    for (int r = 0; r < 4; r++) {
      float ls = lrow[mt][r];
      ls += __shfl_xor(ls, 1);
      ls += __shfl_xor(ls, 2);
      ls += __shfl_xor(ls, 4);
      ls += __shfl_xor(ls, 8);
      float inv = 1.f / ls;
      int qrow = n * Wd + w * 32 + mt * 16 + g * 4 + r;
      if (qrow != 0) {                        // row 0 rewritten by global attn
        unsigned short* dst = Q + headoff + (size_t)qrow * Dsz;
#pragma unroll
        for (int dt = 0; dt < 4; dt++)
          dst[dt * 16 + cl] = f2bu(o[mt][dt][r] * inv);
      }
    }
}

// ==========================================================================
// Global-token attention, split-K flash-decode style (unchanged, proven).
// ==========================================================================
__global__ __launch_bounds__(256) void k_gattn_part(const unsigned short* __restrict__ K,
                                                    const unsigned short* __restrict__ V,
                                                    const unsigned short* __restrict__ Q,
                                                    float* __restrict__ part) {
  __shared__ float q0[64];
  __shared__ float pj[256];
  __shared__ float red[256];
  const int blk = blockIdx.x;
  const int c = blk & (GNS - 1);
  const int h = (blk / GNS) % Hh;
  const int b = blk / (GNS * Hh);
  const int t = threadIdx.x;
  const size_t base = (size_t)b * Ssz * Dsz + (size_t)h * DH;
  if (t < 64) q0[t] = b2f(Q[base + t]);
  __syncthreads();

  const int j = c * 256 + t;
  const uint4* kp = reinterpret_cast<const uint4*>(K + base + (size_t)j * Dsz);
  float acc = 0.f;
#pragma unroll
  for (int u = 0; u < 8; u++) {
    uint4 w = kp[u];
    acc += q0[u*8+0]*b2f_lo(w.x) + q0[u*8+1]*b2f_hi(w.x)
         + q0[u*8+2]*b2f_lo(w.y) + q0[u*8+3]*b2f_hi(w.y)
         + q0[u*8+4]*b2f_lo(w.z) + q0[u*8+5]*b2f_hi(w.z)
         + q0[u*8+6]*b2f_lo(w.w) + q0[u*8+7]*b2f_hi(w.w);
  }
  red[t] = acc;
  __syncthreads();
  for (int s2 = 128; s2 > 0; s2 >>= 1) {
    if (t < s2) red[t] = fmaxf(red[t], red[t + s2]);
    __syncthreads();
  }
  float m = red[0];
  __syncthreads();
  float p = __expf(acc - m);
  pj[t] = p;
  red[t] = p;
  __syncthreads();
  for (int s2 = 128; s2 > 0; s2 >>= 1) {
    if (t < s2) red[t] += red[t + s2];
    __syncthreads();
  }
  float l = red[0];
  __syncthreads();

  const int d  = t & 63;
  const int gq = t >> 6;
  float oa = 0.f;
  for (int jj = gq * 64; jj < gq * 64 + 64; jj++)
    oa += pj[jj] * b2f(V[base + (size_t)(c * 256 + jj) * Dsz + d]);
  red[t] = oa;
  __syncthreads();

  float* P = part + (size_t)((b * Hh + h) * GNS + c) * 66;
  if (t < 64) P[2 + t] = red[t] + red[64 + t] + red[128 + t] + red[192 + t];
  if (t == 0) { P[0] = m; P[1] = l; }
}

__global__ __launch_bounds__(64) void k_gattn_comb(const float* __restrict__ part,
                                                   unsigned short* __restrict__ Q) {
  const int b = blockIdx.x / Hh;
  const int h = blockIdx.x % Hh;
  const int t = threadIdx.x;   // d
  const float* P = part + (size_t)(b * Hh + h) * GNS * 66;
  float M = -1e30f;
#pragma unroll
  for (int cc = 0; cc < GNS; cc++) M = fmaxf(M, P[cc * 66]);
  float L = 0.f, o = 0.f;
#pragma unroll
  for (int cc = 0; cc < GNS; cc++) {
    float e = __expf(P[cc * 66] - M);
    L += P[cc * 66 + 1] * e;
    o += P[cc * 66 + 2 + t] * e;
  }
  const size_t base = (size_t)b * Ssz * Dsz + (size_t)h * DH;
  Q[base + t] = f2bu(o / L);
}

// ---------- residual add + LayerNorm (wave/row), vectorized loads ---------
__global__ __launch_bounds__(256) void k_ln(const unsigned short* __restrict__ x,
                                            const unsigned short* __restrict__ res,
                                            const float* __restrict__ g,
                                            const float* __restrict__ bta,
                                            unsigned short* out) {
  const int row  = blockIdx.x * 4 + (threadIdx.x >> 6);
  const int lane = threadIdx.x & 63;
  const size_t off = (size_t)row * Dsz;
  float v[3][4];
#pragma unroll
  for (int r = 0; r < 3; r++) {
    int d = lane * 4 + r * 256;
    ushort4 xv = *reinterpret_cast<const ushort4*>(x + off + d);
    v[r][0] = b2f(xv.x); v[r][1] = b2f(xv.y);
    v[r][2] = b2f(xv.z); v[r][3] = b2f(xv.w);
    if (res) {
      ushort4 rv = *reinterpret_cast<const ushort4*>(res + off + d);
      v[r][0] += b2f(rv.x); v[r][1] += b2f(rv.y);
      v[r][2] += b2f(rv.z); v[r][3] += b2f(rv.w);
    }
  }
  float s = 0.f;
#pragma unroll
  for (int r = 0; r < 3; r++)
#pragma unroll
    for (int j = 0; j < 4; j++) s += v[r][j];
#pragma unroll
  for (int o2 = 32; o2 > 0; o2 >>= 1) s += __shfl_xor(s, o2);
  float mean = s * (1.f / Dsz);
  float vs = 0.f;
#pragma unroll
  for (int r = 0; r < 3; r++)
#pragma unroll
    for (int j = 0; j < 4; j++) { float dd = v[r][j] - mean; vs += dd * dd; }
#pragma unroll
  for (int o2 = 32; o2 > 0; o2 >>= 1) vs += __shfl_xor(vs, o2);
  float rstd = rsqrtf(vs * (1.f / Dsz) + 1e-5f);
#pragma unroll
  for (int r = 0; r < 3; r++) {
    int d = lane * 4 + r * 256;
    float4 gv = *reinterpret_cast<const float4*>(g + d);
    float4 bv = *reinterpret_cast<const float4*>(bta + d);
    ushort4 ov;
    ov.x = f2bu((v[r][0] - mean) * rstd * gv.x + bv.x);
    ov.y = f2bu((v[r][1] - mean) * rstd * gv.y + bv.y);
    ov.z = f2bu((v[r][2] - mean) * rstd * gv.z + bv.z);
    ov.w = f2bu((v[r][3] - mean) * rstd * gv.w + bv.w);
    *reinterpret_cast<ushort4*>(out + off + d) = ov;
  }
}

// ---------------- host ----------------
static inline unsigned cg8(int n) { return (unsigned)((n / 8 + 255) / 256); }

extern "C" void kernel_launch(void* const* d_in, const int* in_sizes, int n_in,
                              void* d_out, int out_size, void* d_ws, size_t ws_size,
                              hipStream_t stream) {
  const int*   call = (const int*)d_in[0];
  const float* emb  = (const float*)d_in[9];
  const float* Wq = (const float*)d_in[10]; const float* bq = (const float*)d_in[11];
  const float* Wk = (const float*)d_in[12]; const float* bk = (const float*)d_in[13];
  const float* Wv = (const float*)d_in[14]; const float* bv = (const float*)d_in[15];
  const float* Wo = (const float*)d_in[16]; const float* bo = (const float*)d_in[17];
  const float* W1 = (const float*)d_in[18]; const float* b1 = (const float*)d_in[19];
  const float* W2 = (const float*)d_in[20]; const float* b2 = (const float*)d_in[21];
  const float* g1 = (const float*)d_in[22]; const float* bt1 = (const float*)d_in[23];
  const float* g2 = (const float*)d_in[24]; const float* bt2 = (const float*)d_in[25];
  const float* gf = (const float*)d_in[26]; const float* btf = (const float*)d_in[27];
  const float* Wc = (const float*)d_in[28]; const float* bc = (const float*)d_in[29];

  const int DD = Dsz * Dsz;                  // 589824
  const int FD = FFs * Dsz;                  // 2359296
  const int M  = Bsz * Ssz;                  // 32768
  const size_t MD = (size_t)M * Dsz;         // 25165824

  unsigned short* ws = (unsigned short*)d_ws;
  unsigned short* X  = ws;              // MD
  unsigned short* Qb = X  + MD;         // MD
  unsigned short* Kb = Qb + MD;         // MD
  unsigned short* Vb = Kb + MD;         // MD
  unsigned short* cW = Vb + MD;         // 14548992 bf16 weights
  unsigned short* cQKV = cW;                              // [L][3][D][D]
  unsigned short* cWo  = cQKV + (size_t)3 * Ls * DD;
  unsigned short* cW1  = cWo + (size_t)Ls * DD;
  unsigned short* cW2  = cW1 + (size_t)Ls * FD;
  unsigned short* cWc  = cW2 + (size_t)Ls * FD;
  float* gpart = (float*)(cWc + (size_t)Vs * Dsz);   // 96*GNS*66 fp32
  unsigned short* Hb  = Kb;             // FFN intermediate overlays Kb..Vb
  // total ws: 4*MD + 14548992 elems + 406KB = ~220.4 MiB (< proven-safe 240 MiB)

  // weights -> bf16 (once per launch); QKV repacked per-layer-contiguous
  for (int l = 0; l < Ls; l++) {
    k_convw<<<cg8(DD), 256, 0, stream>>>(Wq + (size_t)l*DD, cQKV + (size_t)(l*3+0)*DD, DD);
    k_convw<<<cg8(DD), 256, 0, stream>>>(Wk + (size_t)l*DD, cQKV + (size_t)(l*3+1)*DD, DD);
    k_convw<<<cg8(DD), 256, 0, stream>>>(Wv + (size_t)l*DD, cQKV + (size_t)(l*3+2)*DD, DD);
  }
  k_convw<<<cg8(Ls*DD), 256, 0, stream>>>(Wo, cWo, Ls*DD);
  k_convw<<<cg8(Ls*FD), 256, 0, stream>>>(W1, cW1, Ls*FD);
  k_convw<<<cg8(Ls*FD), 256, 0, stream>>>(W2, cW2, Ls*FD);
  k_convw<<<cg8(Vs*Dsz), 256, 0, stream>>>(Wc, cWc, Vs*Dsz);

  k_embed<<<(unsigned)(M * 96 / 256), 256, 0, stream>>>(call, emb, X);

  for (int l = 0; l < Ls; l++) {
    // fused QKV: N=2304 (groups of 768 -> Qb, Kb, Vb); Q scaled by 1/8
    k_gemm256<<<dim3(2304/256, M/256), 512, 0, stream>>>(X, cQKV + (size_t)l*3*DD,
        bq + l*Dsz, bk + l*Dsz, bv + l*Dsz, Qb, Kb, Vb,
        M, 2304, Dsz, Dsz, 0.125f, 1.f, 1.f, 0, 0);
    // global-attn partials read Q row 0 (band attn never writes row 0)
    k_gattn_part<<<Bsz * Hh * GNS, 256, 0, stream>>>(Kb, Vb, Qb, gpart);
    k_band_attn<<<Bsz * Hh * NBl, 256, 0, stream>>>(Kb, Vb, Qb);
    k_gattn_comb<<<Bsz * Hh, 64, 0, stream>>>(gpart, Qb);
    // attn projection: Qb @ Wo -> Kb (K dead after attention)
    k_gemm256<<<dim3(Dsz/256, M/256), 512, 0, stream>>>(Qb, cWo + (size_t)l*DD,
        bo + l*Dsz, bo + l*Dsz, bo + l*Dsz, Kb, Kb, Kb,
        M, Dsz, Dsz, Dsz, 1.f, 1.f, 1.f, 0, 0);
    k_ln<<<M/4, 256, 0, stream>>>(X, Kb, g1 + l*Dsz, bt1 + l*Dsz, X);
    for (int hf = 0; hf < 2; hf++) {
      const size_t mo = (size_t)hf * (M/2);
      k_gemm256<<<dim3(FFs/256, (M/2)/256), 512, 0, stream>>>(X + mo*Dsz,
          cW1 + (size_t)l*FD, b1 + l*FFs, b1 + l*FFs, b1 + l*FFs, Hb, Hb, Hb,
          M/2, FFs, Dsz, FFs, 1.f, 1.f, 1.f, 1, 0);
      k_gemm256<<<dim3(Dsz/256, (M/2)/256), 512, 0, stream>>>(Hb,
          cW2 + (size_t)l*FD, b2 + l*Dsz, b2 + l*Dsz, b2 + l*Dsz,
          Qb + mo*Dsz, Qb + mo*Dsz, Qb + mo*Dsz,
          M/2, Dsz, FFs, Dsz, 1.f, 1.f, 1.f, 0, 0);
    }
    k_ln<<<M/4, 256, 0, stream>>>(X, Qb, g2 + l*Dsz, bt2 + l*Dsz, X);
  }

  k_ln<<<M/4, 256, 0, stream>>>(X, nullptr, gf, btf, Qb);
  k_gemm256<<<dim3(Vs/256, M/256), 512, 0, stream>>>(Qb, cWc,
      bc, bc, bc, (float*)d_out, (float*)d_out, (float*)d_out,
      M, Vs, Dsz, Vs, 1.f, 1.f, 1.f, 0, 1);
}